// Round 6
// baseline (521.714 us; speedup 1.0000x reference)
//
#include <hip/hip_runtime.h>
#include <hip/hip_bf16.h>
#include <cmath>

typedef __hip_bfloat16 bf16;
typedef __bf16 bf16x8 __attribute__((ext_vector_type(8)));
typedef float floatx4 __attribute__((ext_vector_type(4)));

__device__ inline floatx4 mfma16(bf16x8 a, bf16x8 b, floatx4 c) {
  return __builtin_amdgcn_mfma_f32_16x16x32_bf16(a, b, c, 0, 0, 0);
}

// async global->LDS, 16B/lane; lds dest must be wave-uniform (HW adds lane*16)
__device__ inline void async_ld16(const void* g, void* l) {
  __builtin_amdgcn_global_load_lds((const __attribute__((address_space(1))) void*)g,
                                   (__attribute__((address_space(3))) void*)l,
                                   16, 0, 0);
}

// pack 8 fp32 -> 8 bf16 (RNE) -> one 16B store
__device__ inline uint4 pack8(float4 a, float4 b) {
  union { uint4 u; bf16 h[8]; } t;
  t.h[0] = __float2bfloat16(a.x); t.h[1] = __float2bfloat16(a.y);
  t.h[2] = __float2bfloat16(a.z); t.h[3] = __float2bfloat16(a.w);
  t.h[4] = __float2bfloat16(b.x); t.h[5] = __float2bfloat16(b.y);
  t.h[6] = __float2bfloat16(b.z); t.h[7] = __float2bfloat16(b.w);
  return t.u;
}

// bulk fp32 -> bf16 convert, 8 elems/thread
__global__ __launch_bounds__(256)
void cvt_f32_bf16(const float* __restrict__ s, bf16* __restrict__ d, int n8) {
  const int i = blockIdx.x * 256 + threadIdx.x;
  if (i >= n8) return;
  const float4 a = ((const float4*)s)[2 * i];
  const float4 b = ((const float4*)s)[2 * i + 1];
  ((uint4*)d)[i] = pack8(a, b);
}

// ball[5120] = concat(bq[4096], bk[512], bv[512])
__global__ void concat_bias3(const float* __restrict__ q, const float* __restrict__ k,
                             const float* __restrict__ v, float* __restrict__ o) {
  const int i = blockIdx.x * 256 + threadIdx.x;  // 5120 threads
  if (i < 4096) o[i] = q[i];
  else if (i < 4608) o[i] = k[i - 4096];
  else o[i] = v[i - 4608];
}

// Q pre-scale: 1/sqrt(64) * log2(e)  -> softmax runs in exp2 domain
#define QSCALE 0.1803368801111601f

// ---------------------------------------------------------------------------
// Double-buffered 128x128 GEMM, A = bf16 (async DMA), B = fp32 WEIGHTS read
// directly (reg-load -> pack8 -> LDS), eliminating the per-iteration weight
// cvt kernels (~158 MB traffic + 4 launches).
// Round-11 notes: round-10's 128x64 tiles REGRESSED (FETCH 174 MB = 4.2x
// over-fetch, 125 us/GEMM) — reverted to 128x128 (round-9 config, <109 us).
// Pipeline per K-step (2 barriers, no same-iteration issue->drain):
//   barrier1: drains A-DMA(kt) + B-fp32-loads(kt) [issued one phase earlier]
//   ds_write packed B(kt) (linear tid*16 layout = conflict-free, DMA-like)
//   barrier2: writes visible; outstanding vmem = 0 -> its vmcnt(0) is free
//   issue A-DMA(kt+1) + B-loads(kt+1)   [in flight through compute(kt)]
//   compute(kt)
// OUT_MODE 4: B = Wq|Wk|Wv fp32 (segments 128-aligned -> block-uniform select);
//             routes Q (scaled) / K / V-transposed.  OUT_MODE 1: fp32 C.
// XCD-aware swizzle (x-major), grids 640/368 blocks (%8==0, bijective).
// ---------------------------------------------------------------------------
template <int OUT_MODE>
__global__ __launch_bounds__(256)
void gemm_bf32(const bf16* __restrict__ A, const float* __restrict__ Bq,
               const float* __restrict__ Bk, const float* __restrict__ Bv,
               const float* __restrict__ bias, void* __restrict__ Cp,
               void* __restrict__ Cqp, void* __restrict__ Ctp,
               int M, int N, int K, float qmul) {
  __shared__ __align__(16) bf16 sA[2][128 * 32];
  __shared__ __align__(16) bf16 sB[2][128 * 32];
  const int tid  = threadIdx.x;
  const int wave = tid >> 6;
  const int lane = tid & 63;
  const int quad = lane >> 4;
  const int l15  = lane & 15;

  // XCD-aware swizzle: XCD k owns a contiguous logical-tile range (x-major)
  const int nwg = gridDim.x * gridDim.y;
  const int lin = blockIdx.y * gridDim.x + blockIdx.x;
  const int L   = (lin & 7) * (nwg >> 3) + (lin >> 3);
  const int bm  = (L / gridDim.x) * 128;
  const int bn  = (L % gridDim.x) * 128;

  const int wm = (wave & 1) * 64;
  const int wn = (wave >> 1) * 64;

  floatx4 acc[4][4] = {};

  const int g0 = tid, g1 = tid + 256;
  const int arow0 = bm + (g0 >> 2), acol0 = (g0 & 3) * 8;
  const int arow1 = bm + (g1 >> 2), acol1 = (g1 & 3) * 8;
  int brow0 = bn + (g0 >> 2); if (brow0 >= N) brow0 = N - 1;  // N edge: clamp (stores guarded)
  int brow1 = bn + (g1 >> 2); if (brow1 >= N) brow1 = N - 1;

  // B segment select (block-uniform: tiles never straddle 128-aligned segments)
  const float* B = Bq; int bro = 0;
  if (OUT_MODE == 4) {
    if (bn >= 4608)      { B = Bv; bro = 4608; }
    else if (bn >= 4096) { B = Bk; bro = 4096; }
  }
  const float* bp0 = B + (size_t)(brow0 - bro) * K + acol0;
  const float* bp1 = B + (size_t)(brow1 - bro) * K + acol1;

  const int nk = K >> 5;
  // prologue: tile 0 (A via DMA, B via fp32 reg loads)
  async_ld16(A + (size_t)arow0 * K + acol0, &sA[0][wave * 512]);
  async_ld16(A + (size_t)arow1 * K + acol1, &sA[0][2048 + wave * 512]);
  float4 f00 = *(const float4*)(bp0);
  float4 f01 = *(const float4*)(bp0 + 4);
  float4 f10 = *(const float4*)(bp1);
  float4 f11 = *(const float4*)(bp1 + 4);

  for (int kt = 0; kt < nk; ++kt) {
    const int cur = kt & 1;
    __syncthreads();  // drains A-DMA(kt) + B-loads(kt); sB[cur] last read in kt-2
    *(uint4*)(&sB[cur][tid * 8])        = pack8(f00, f01);
    *(uint4*)(&sB[cur][2048 + tid * 8]) = pack8(f10, f11);
    __syncthreads();  // ds_writes visible; no outstanding vmem here (vmcnt free)
    if (kt + 1 < nk) {
      const int k0 = (kt + 1) << 5;
      const int nb = (kt + 1) & 1;
      async_ld16(A + (size_t)arow0 * K + k0 + acol0, &sA[nb][wave * 512]);
      async_ld16(A + (size_t)arow1 * K + k0 + acol1, &sA[nb][2048 + wave * 512]);
      f00 = *(const float4*)(bp0 + k0);
      f01 = *(const float4*)(bp0 + k0 + 4);
      f10 = *(const float4*)(bp1 + k0);
      f11 = *(const float4*)(bp1 + k0 + 4);
    }
    const bf16* a = sA[cur];
    const bf16* b = sB[cur];

    bf16x8 aF[4], bF[4];
#pragma unroll
    for (int mi = 0; mi < 4; ++mi)
      aF[mi] = *(const bf16x8*)(a + (wm + mi * 16 + l15) * 32 + quad * 8);
#pragma unroll
    for (int ni = 0; ni < 4; ++ni)
      bF[ni] = *(const bf16x8*)(b + (wn + ni * 16 + l15) * 32 + quad * 8);
#pragma unroll
    for (int mi = 0; mi < 4; ++mi)
#pragma unroll
      for (int ni = 0; ni < 4; ++ni)
        acc[mi][ni] = mfma16(aF[mi], bF[ni], acc[mi][ni]);
  }

  // epilogue: C/D layout col=lane&15, row=quad*4+reg (m89-verified)
#pragma unroll
  for (int ni = 0; ni < 4; ++ni) {
    const int col = bn + wn + ni * 16 + l15;
    if (col >= N) continue;
    const float bv = bias[col];
#pragma unroll
    for (int mi = 0; mi < 4; ++mi) {
      const int row = bm + wm + mi * 16 + quad * 4;
#pragma unroll
      for (int r = 0; r < 4; ++r) {
        const float val = acc[mi][ni][r] + bv;
        if (OUT_MODE == 1) {
          ((float*)Cp)[(size_t)(row + r) * N + col] = val;
        } else {  // fused QKV routing (segment uniform across the 16-lane store group)
          if (col < 4096)      ((bf16*)Cp)[(size_t)(row + r) * 4096 + col] = __float2bfloat16(val * qmul);
          else if (col < 4608) ((bf16*)Cqp)[(size_t)(row + r) * 512 + (col - 4096)] = __float2bfloat16(val);
          else                 ((bf16*)Ctp)[(size_t)(col - 4608) * M + row + r] = __float2bfloat16(val);
        }
      }
    }
  }
}

// ---------------------------------------------------------------------------
// Fallback-path GEMM (fp32 inputs staged in-kernel). Unchanged, verified.
// ---------------------------------------------------------------------------
template <int A_BF, int B_BF, int OUT_MODE>
__global__ __launch_bounds__(256)
void gemm_bt_bias(const void* __restrict__ Ap, const void* __restrict__ Bp,
                  const float* __restrict__ bias, void* __restrict__ Cp,
                  void* __restrict__ Cqp, void* __restrict__ Ctp,
                  int M, int N, int K, float qmul) {
  __shared__ __align__(16) bf16 sA[128 * 32];
  __shared__ __align__(16) bf16 sB[128 * 32];
  const int tid  = threadIdx.x;
  const int wave = tid >> 6;
  const int lane = tid & 63;
  const int quad = lane >> 4;
  const int l15  = lane & 15;
  const int bm = blockIdx.y * 128;
  const int bn = blockIdx.x * 128;
  const int wm = (wave & 1) * 64;
  const int wn = (wave >> 1) * 64;

  floatx4 acc[4][4] = {};

  const int g0 = tid, g1 = tid + 256;
  const int arow0 = bm + (g0 >> 2), acol0 = (g0 & 3) * 8;
  const int arow1 = bm + (g1 >> 2), acol1 = (g1 & 3) * 8;
  int brow0 = bn + (g0 >> 2); if (brow0 >= N) brow0 = N - 1;
  int brow1 = bn + (g1 >> 2); if (brow1 >= N) brow1 = N - 1;

  for (int k0 = 0; k0 < K; k0 += 32) {
    __syncthreads();
    if (A_BF) {
      const bf16* A = (const bf16*)Ap;
      async_ld16(A + (size_t)arow0 * K + k0 + acol0, sA + wave * 512);
      async_ld16(A + (size_t)arow1 * K + k0 + acol1, sA + 2048 + wave * 512);
    } else {
      const float* A = (const float*)Ap;
      const float* p0 = A + (size_t)arow0 * K + k0 + acol0;
      const float* p1 = A + (size_t)arow1 * K + k0 + acol1;
      *(uint4*)(sA + tid * 8)        = pack8(*(const float4*)p0, *(const float4*)(p0 + 4));
      *(uint4*)(sA + 2048 + tid * 8) = pack8(*(const float4*)p1, *(const float4*)(p1 + 4));
    }
    if (B_BF) {
      const bf16* B = (const bf16*)Bp;
      async_ld16(B + (size_t)brow0 * K + k0 + acol0, sB + wave * 512);
      async_ld16(B + (size_t)brow1 * K + k0 + acol1, sB + 2048 + wave * 512);
    } else {
      const float* B = (const float*)Bp;
      const float* p0 = B + (size_t)brow0 * K + k0 + acol0;
      const float* p1 = B + (size_t)brow1 * K + k0 + acol1;
      *(uint4*)(sB + tid * 8)        = pack8(*(const float4*)p0, *(const float4*)(p0 + 4));
      *(uint4*)(sB + 2048 + tid * 8) = pack8(*(const float4*)p1, *(const float4*)(p1 + 4));
    }
    __syncthreads();

    bf16x8 aF[4], bF[4];
#pragma unroll
    for (int mi = 0; mi < 4; ++mi)
      aF[mi] = *(const bf16x8*)(sA + (wm + mi * 16 + l15) * 32 + quad * 8);
#pragma unroll
    for (int ni = 0; ni < 4; ++ni)
      bF[ni] = *(const bf16x8*)(sB + (wn + ni * 16 + l15) * 32 + quad * 8);
#pragma unroll
    for (int mi = 0; mi < 4; ++mi)
#pragma unroll
      for (int ni = 0; ni < 4; ++ni)
        acc[mi][ni] = mfma16(aF[mi], bF[ni], acc[mi][ni]);
  }

#pragma unroll
  for (int ni = 0; ni < 4; ++ni) {
    const int col = bn + wn + ni * 16 + l15;
    if (col >= N) continue;
    const float bv = bias[col];
#pragma unroll
    for (int mi = 0; mi < 4; ++mi) {
      const int row = bm + wm + mi * 16 + quad * 4;
#pragma unroll
      for (int r = 0; r < 4; ++r) {
        const float val = acc[mi][ni][r] + bv;
        if (OUT_MODE == 0) {
          ((bf16*)Cp)[(size_t)(row + r) * N + col] = __float2bfloat16(val * qmul);
        } else if (OUT_MODE == 1) {
          ((float*)Cp)[(size_t)(row + r) * N + col] = val;
        } else if (OUT_MODE == 2) {
          ((bf16*)Ctp)[(size_t)col * M + row + r] = __float2bfloat16(val);
        }
      }
    }
  }
}

// Fused causal GQA attention, flash-style online softmax (exp2 domain; Q pre-scaled).
// 4 waves; swapped MFMA operands: query is lane-local (see round-8 notes).
// XCD-aware block swizzle — XCD k owns heads 8k..8k+7 (one KV group, 512 KB,
// L2-resident per XCD; verified round-9: FETCH 22.9 -> 10.3 GB, 153 -> 108 us).
__global__ __launch_bounds__(256)
void attn_fused(const bf16* __restrict__ Q, const bf16* __restrict__ Kc,
                const bf16* __restrict__ Vt, bf16* __restrict__ AO) {
  constexpr int HD = 4096, KD = 512, SEQ = 2048;
  constexpr float NEG = -1e30f;
  __shared__ __align__(16) bf16 sP[64 * 64];       // [query][key], swizzled granules
  __shared__ __align__(16) bf16 sK[2][64 * 64];    // [t][d], swizzled granules
  __shared__ __align__(16) bf16 sV[2][64 * 64];    // [d][t], swizzled granules

  // grid (32, 64) -> 2048 blocks; XCD swizzle: L = (lin&7)*256 + lin>>3
  const int lin = blockIdx.y * 32 + blockIdx.x;
  const int L   = (lin & 7) * 256 + (lin >> 3);
  const int h   = L >> 5;                           // heads 8k..8k+7 on XCD k
  const int qb  = 31 - (L & 31);                    // heavy blocks first within head
  const int kvh = h >> 3;        // h // G, G=8
  const int tid = threadIdx.x, wave = tid >> 6, lane = tid & 63;
  const int quad = lane >> 4, l15 = lane & 15;
  const int sq0 = qb * 64;

  // DMA decomposition: chunk c = wave*2+i covers tile rows 8c..8c+7.
  const int lrow = lane >> 3;
  const int lgr  = (lane & 7) ^ lrow;

  // Q fragments straight to registers (lane l15 = query row wave*16+l15)
  bf16x8 qf[2];
#pragma unroll
  for (int ks = 0; ks < 2; ++ks)
    qf[ks] = *(const bf16x8*)(Q + (size_t)(sq0 + wave * 16 + l15) * HD + h * 64 + ks * 32 + quad * 8);

  // ones A-fragment for the key-sum MFMA (denominator)
  bf16x8 onesf;
#pragma unroll
  for (int i = 0; i < 8; ++i) onesf[i] = (__bf16)1.0f;

  // prologue: DMA tile 0 into buffer 0
#pragma unroll
  for (int i = 0; i < 2; ++i) {
    const int c = wave * 2 + i;
    async_ld16(Kc + (size_t)(c * 8 + lrow) * KD + kvh * 64 + lgr * 8, &sK[0][c * 512]);
    async_ld16(Vt + (size_t)(kvh * 64 + c * 8 + lrow) * SEQ + lgr * 8, &sV[0][c * 512]);
  }

  floatx4 o_acc[4] = {};   // O^T: lane = query, o_acc[di][r] = O[q][di*16+quad*4+r]
  floatx4 o_sum = {};      // denominator (all 4 regs equal), lane = query
  float m_run = NEG;       // per-lane scalar running max (lane's query)

  for (int kt = 0; kt <= qb; ++kt) {   // analytic causality: skip fully-masked key tiles
    const int st0 = kt * 64;
    __syncthreads();  // drains tile-kt DMA (vmcnt) for all waves; protects buffer reuse

    if (kt < qb) {    // issue tile kt+1 DMA; in flight through this compute phase
      const int st1 = st0 + 64;
      const int nb = (kt + 1) & 1;
#pragma unroll
      for (int i = 0; i < 2; ++i) {
        const int c = wave * 2 + i;
        async_ld16(Kc + (size_t)(st1 + c * 8 + lrow) * KD + kvh * 64 + lgr * 8, &sK[nb][c * 512]);
        async_ld16(Vt + (size_t)(kvh * 64 + c * 8 + lrow) * SEQ + st1 + lgr * 8, &sV[nb][c * 512]);
      }
    }
    const bf16* kb = sK[kt & 1];
    const bf16* vb = sV[kt & 1];

    // S^T = K Q^T : lane l15 = query, s_acc[ni][r] = key st0+ni*16+quad*4+r
    floatx4 s_acc[4] = {};
#pragma unroll
    for (int ks = 0; ks < 2; ++ks) {
#pragma unroll
      for (int ni = 0; ni < 4; ++ni) {
        const bf16x8 kF = *(const bf16x8*)(kb + (ni * 16 + l15) * 64 + (((ks * 4 + quad) ^ (l15 & 7)) * 8));
        s_acc[ni] = mfma16(kF, qf[ks], s_acc[ni]);
      }
    }

    if (kt == qb) {   // diagonal tile only: causal mask key > query (wave-uniform branch)
      const int qloc = wave * 16 + l15;
#pragma unroll
      for (int ni = 0; ni < 4; ++ni)
#pragma unroll
        for (int r = 0; r < 4; ++r)
          if (ni * 16 + quad * 4 + r > qloc) s_acc[ni][r] = NEG;
    }

    // row max: 15 lane-local fmax (tree) + 2 cross-quad shfl
    float t0 = fmaxf(fmaxf(s_acc[0][0], s_acc[0][1]), fmaxf(s_acc[0][2], s_acc[0][3]));
    float t1 = fmaxf(fmaxf(s_acc[1][0], s_acc[1][1]), fmaxf(s_acc[1][2], s_acc[1][3]));
    float t2 = fmaxf(fmaxf(s_acc[2][0], s_acc[2][1]), fmaxf(s_acc[2][2], s_acc[2][3]));
    float t3 = fmaxf(fmaxf(s_acc[3][0], s_acc[3][1]), fmaxf(s_acc[3][2], s_acc[3][3]));
    float tm = fmaxf(fmaxf(t0, t1), fmaxf(t2, t3));
    tm = fmaxf(tm, __shfl_xor(tm, 16));
    tm = fmaxf(tm, __shfl_xor(tm, 32));

    // defer-max: rescale only when some lane's max grew by > 8 (exp2 domain)
    if (!__all(tm - m_run <= 8.0f)) {
      const float mn = fmaxf(m_run, tm);
      const float alpha = exp2f(m_run - mn);
      m_run = mn;
#pragma unroll
      for (int r = 0; r < 4; ++r) o_sum[r] *= alpha;
#pragma unroll
      for (int di = 0; di < 4; ++di)
#pragma unroll
        for (int r = 0; r < 4; ++r) o_acc[di][r] *= alpha;
    }

    // P[query][key] -> swizzled sP; 4 consecutive keys pack into one b64 write
    const int prow = wave * 16 + l15;
#pragma unroll
    for (int ni = 0; ni < 4; ++ni) {
      union { uint2 u; bf16 hh[4]; } pk;
#pragma unroll
      for (int r = 0; r < 4; ++r)
        pk.hh[r] = __float2bfloat16(exp2f(s_acc[ni][r] - m_run));
      const int g = ni * 2 + (quad >> 1);
      *(uint2*)(sP + prow * 64 + ((g ^ (l15 & 7)) * 8) + (quad & 1) * 4) = pk.u;
    }

    // O^T += V^T P : lane = query; V reads identical pattern to QK^T's K reads
#pragma unroll
    for (int ks = 0; ks < 2; ++ks) {
      const bf16x8 pF = *(const bf16x8*)(sP + prow * 64 + (((ks * 4 + quad) ^ (l15 & 7)) * 8));
#pragma unroll
      for (int di = 0; di < 4; ++di) {
        const bf16x8 vF = *(const bf16x8*)(vb + (di * 16 + l15) * 64 + (((ks * 4 + quad) ^ (l15 & 7)) * 8));
        o_acc[di] = mfma16(vF, pF, o_acc[di]);
      }
      o_sum = mfma16(onesf, pF, o_sum);   // key-sum on the matrix pipe
    }
  }

  // normalize (1 rcp per lane) + packed 8B stores to AO[q][h*64+d]
  const float inv = 1.0f / o_sum[0];
  const int row = sq0 + wave * 16 + l15;
#pragma unroll
  for (int di = 0; di < 4; ++di) {
    union { uint2 u; bf16 hh[4]; } pk;
#pragma unroll
    for (int r = 0; r < 4; ++r)
      pk.hh[r] = __float2bfloat16(o_acc[di][r] * inv);
    *(uint2*)(AO + (size_t)row * HD + h * 64 + di * 16 + quad * 4) = pk.u;
  }
}

extern "C" void kernel_launch(void* const* d_in, const int* in_sizes, int n_in,
                              void* d_out, int out_size, void* d_ws, size_t ws_size,
                              hipStream_t stream) {
  const float* X  = (const float*)d_in[0];   // [2048, 2880]
  // d_in[1] = attention_mask: exactly causal -> handled analytically
  const float* Wq = (const float*)d_in[2];   // [4096, 2880]
  const float* bq = (const float*)d_in[3];
  const float* Wk = (const float*)d_in[4];   // [512, 2880]
  const float* bk = (const float*)d_in[5];
  const float* Wv = (const float*)d_in[6];
  const float* bv = (const float*)d_in[7];
  const float* Wo = (const float*)d_in[8];   // [2880, 4096]
  const float* bo = (const float*)d_in[9];
  float* out = (float*)d_out;                // [2048, 2880] fp32

  char* ws = (char*)d_ws;
  bf16* Qb = (bf16*)(ws);                          // 16 MiB
  bf16* Kb = (bf16*)(ws + 16777216);               // [2048][512]  2 MiB
  bf16* Vt = (bf16*)(ws + 18874368);               // [512][2048]  2 MiB (transposed)
  bf16* AO = (bf16*)(ws + 20971520);               // 16 MiB
  // fast-path extras
  bf16*  Xb   = (bf16*)(ws + 37748736);            // 11.25 MiB
  float* ball = (float*)(ws + 49545216);           // 20 KiB
  const size_t NEED = 49565696;

  dim3 blk(256);
  if (ws_size >= NEED) {
    // X -> bf16 once; weights consumed fp32 directly inside the GEMMs
    cvt_f32_bf16<<<dim3(2048 * 2880 / 8 / 256), blk, 0, stream>>>(X, Xb, 2048 * 2880 / 8);
    concat_bias3<<<dim3(20), blk, 0, stream>>>(bq, bk, bv, ball);

    // fused QKV projection: N = 4096 + 512 + 512; Q segment pre-scaled
    gemm_bf32<4><<<dim3(40, 16), blk, 0, stream>>>(Xb, Wq, Wk, Wv, ball, Qb, Kb, Vt, 2048, 5120, 2880, QSCALE);
    attn_fused<<<dim3(32, 64), blk, 0, stream>>>(Qb, Kb, Vt, AO);
    gemm_bf32<1><<<dim3(23, 16), blk, 0, stream>>>(AO, Wo, nullptr, nullptr, bo, out, nullptr, nullptr, 2048, 2880, 4096, 1.f);
  } else {
    // fallback: fp32 staging in-GEMM (round-3 verified path), V written transposed
    gemm_bt_bias<0, 0, 0><<<dim3(32, 16), blk, 0, stream>>>(X, Wq, bq, Qb, nullptr, nullptr, 2048, 4096, 2880, QSCALE);
    gemm_bt_bias<0, 0, 0><<<dim3(4, 16),  blk, 0, stream>>>(X, Wk, bk, Kb, nullptr, nullptr, 2048, 512, 2880, 1.f);
    gemm_bt_bias<0, 0, 2><<<dim3(4, 16),  blk, 0, stream>>>(X, Wv, bv, nullptr, nullptr, Vt, 2048, 512, 2880, 1.f);
    attn_fused<<<dim3(32, 64), blk, 0, stream>>>(Qb, Kb, Vt, AO);
    gemm_bt_bias<1, 0, 1><<<dim3(23, 16), blk, 0, stream>>>(AO, Wo, bo, out, nullptr, nullptr, 2048, 2880, 4096, 1.f);
  }
}

// Round 7
// 440.736 us; speedup vs baseline: 1.1837x; 1.1837x over previous
//
#include <hip/hip_runtime.h>
#include <hip/hip_bf16.h>
#include <cmath>

typedef __hip_bfloat16 bf16;
typedef __bf16 bf16x8 __attribute__((ext_vector_type(8)));
typedef float floatx4 __attribute__((ext_vector_type(4)));

__device__ inline floatx4 mfma16(bf16x8 a, bf16x8 b, floatx4 c) {
  return __builtin_amdgcn_mfma_f32_16x16x32_bf16(a, b, c, 0, 0, 0);
}

// async global->LDS, 16B/lane; lds dest must be wave-uniform (HW adds lane*16)
__device__ inline void async_ld16(const void* g, void* l) {
  __builtin_amdgcn_global_load_lds((const __attribute__((address_space(1))) void*)g,
                                   (__attribute__((address_space(3))) void*)l,
                                   16, 0, 0);
}

// pack 8 fp32 -> 8 bf16 (RNE) -> one 16B store
__device__ inline uint4 pack8(float4 a, float4 b) {
  union { uint4 u; bf16 h[8]; } t;
  t.h[0] = __float2bfloat16(a.x); t.h[1] = __float2bfloat16(a.y);
  t.h[2] = __float2bfloat16(a.z); t.h[3] = __float2bfloat16(a.w);
  t.h[4] = __float2bfloat16(b.x); t.h[5] = __float2bfloat16(b.y);
  t.h[6] = __float2bfloat16(b.z); t.h[7] = __float2bfloat16(b.w);
  return t.u;
}

__device__ inline void cvt_region(const float* __restrict__ s, bf16* __restrict__ d, int i) {
  const float4 a = ((const float4*)s)[2 * i];
  const float4 b = ((const float4*)s)[2 * i + 1];
  ((uint4*)d)[i] = pack8(a, b);
}

// Round-12: ONE cvt kernel for X + all weights (was 5 launches + concat).
// Region dispatch by blockIdx; all region sizes are exact multiples of
// 2048 elems (256 thr x 8): X 2880 blks, Wq 5760, Wk 720, Wv 720, Wo 5760.
__global__ __launch_bounds__(256)
void cvt_all(const float* __restrict__ X,  const float* __restrict__ Wq,
             const float* __restrict__ Wk, const float* __restrict__ Wv,
             const float* __restrict__ Wo, bf16* __restrict__ Xb,
             bf16* __restrict__ Wall, bf16* __restrict__ Wob) {
  const int blk = blockIdx.x;
  const int tid = threadIdx.x;
  if (blk < 2880) {
    cvt_region(X, Xb, blk * 256 + tid);
  } else if (blk < 8640) {
    cvt_region(Wq, Wall, (blk - 2880) * 256 + tid);
  } else if (blk < 9360) {
    cvt_region(Wk, Wall + (size_t)4096 * 2880, (blk - 8640) * 256 + tid);
  } else if (blk < 10080) {
    cvt_region(Wv, Wall + (size_t)4608 * 2880, (blk - 9360) * 256 + tid);
  } else {
    cvt_region(Wo, Wob, (blk - 10080) * 256 + tid);
  }
}

// Q pre-scale: 1/sqrt(64) * log2(e)  -> softmax runs in exp2 domain
#define QSCALE 0.1803368801111601f

// ---------------------------------------------------------------------------
// Double-buffered bf16 GEMM, 128x128 tiles (round-4 verified config; round-10's
// 128x64 and round-11's direct-fp32-B both REGRESSED — over-fetch on the
// re-swept operand dominates; bf16 cvt once is cheaper).
// Pipeline: prologue-issue tile 0; per-iter issue tile kt+1 into buf^1,
// compute tile kt, single loop-top barrier drains (attn_fused's proven scheme).
// XCD-aware swizzle (x-major, nwg % 8 == 0 for both launches).
// Bias read directly per-segment (concat kernel eliminated).
// OUT_MODE: 1 = fp32 [M][N] (+b0); 4 = fused QKV route: Q (scaled, +b0) /
//           K (+b1) / V transposed (+b2).
// ---------------------------------------------------------------------------
template <int OUT_MODE>
__global__ __launch_bounds__(256)
void gemm_bt_db(const bf16* __restrict__ A, const bf16* __restrict__ B,
                const float* __restrict__ b0, const float* __restrict__ b1,
                const float* __restrict__ b2, void* __restrict__ Cp,
                void* __restrict__ Cqp, void* __restrict__ Ctp,
                int M, int N, int K, float qmul) {
  __shared__ __align__(16) bf16 sA[2][128 * 32];
  __shared__ __align__(16) bf16 sB[2][128 * 32];
  const int tid  = threadIdx.x;
  const int wave = tid >> 6;
  const int lane = tid & 63;
  const int quad = lane >> 4;
  const int l15  = lane & 15;

  // XCD-aware swizzle: XCD k owns a contiguous logical-tile range (x-major)
  const int nwg = gridDim.x * gridDim.y;
  const int lin = blockIdx.y * gridDim.x + blockIdx.x;
  const int L   = (lin & 7) * (nwg >> 3) + (lin >> 3);
  const int bm  = (L / gridDim.x) * 128;
  const int bn  = (L % gridDim.x) * 128;

  const int wm = (wave & 1) * 64;
  const int wn = (wave >> 1) * 64;

  floatx4 acc[4][4] = {};

  const int g0 = tid, g1 = tid + 256;
  const int arow0 = bm + (g0 >> 2), acol0 = (g0 & 3) * 8;
  const int arow1 = bm + (g1 >> 2), acol1 = (g1 & 3) * 8;
  int brow0 = bn + (g0 >> 2); if (brow0 >= N) brow0 = N - 1;  // N edge: clamp (stores guarded)
  int brow1 = bn + (g1 >> 2); if (brow1 >= N) brow1 = N - 1;

  const int nk = K >> 5;
  // prologue: tile 0 -> buffer 0
  async_ld16(A + (size_t)arow0 * K + acol0, &sA[0][wave * 512]);
  async_ld16(A + (size_t)arow1 * K + acol1, &sA[0][2048 + wave * 512]);
  async_ld16(B + (size_t)brow0 * K + acol0, &sB[0][wave * 512]);
  async_ld16(B + (size_t)brow1 * K + acol1, &sB[0][2048 + wave * 512]);

  for (int kt = 0; kt < nk; ++kt) {
    __syncthreads();  // drains tile-kt DMA (vmcnt) for all waves; protects buf^1 reuse
    if (kt + 1 < nk) {
      const int k0 = (kt + 1) << 5;
      const int nb = (kt + 1) & 1;
      async_ld16(A + (size_t)arow0 * K + k0 + acol0, &sA[nb][wave * 512]);
      async_ld16(A + (size_t)arow1 * K + k0 + acol1, &sA[nb][2048 + wave * 512]);
      async_ld16(B + (size_t)brow0 * K + k0 + acol0, &sB[nb][wave * 512]);
      async_ld16(B + (size_t)brow1 * K + k0 + acol1, &sB[nb][2048 + wave * 512]);
    }
    const bf16* a = sA[kt & 1];
    const bf16* b = sB[kt & 1];

    bf16x8 aF[4], bF[4];
#pragma unroll
    for (int mi = 0; mi < 4; ++mi)
      aF[mi] = *(const bf16x8*)(a + (wm + mi * 16 + l15) * 32 + quad * 8);
#pragma unroll
    for (int ni = 0; ni < 4; ++ni)
      bF[ni] = *(const bf16x8*)(b + (wn + ni * 16 + l15) * 32 + quad * 8);
#pragma unroll
    for (int mi = 0; mi < 4; ++mi)
#pragma unroll
      for (int ni = 0; ni < 4; ++ni)
        acc[mi][ni] = mfma16(aF[mi], bF[ni], acc[mi][ni]);
  }

  // epilogue: C/D layout col=lane&15, row=quad*4+reg (m89-verified)
#pragma unroll
  for (int ni = 0; ni < 4; ++ni) {
    const int col = bn + wn + ni * 16 + l15;
    if (col >= N) continue;
    float bv;
    if (OUT_MODE == 4)
      bv = (col < 4096) ? b0[col] : (col < 4608 ? b1[col - 4096] : b2[col - 4608]);
    else
      bv = b0[col];
#pragma unroll
    for (int mi = 0; mi < 4; ++mi) {
      const int row = bm + wm + mi * 16 + quad * 4;
#pragma unroll
      for (int r = 0; r < 4; ++r) {
        const float val = acc[mi][ni][r] + bv;
        if (OUT_MODE == 1) {
          ((float*)Cp)[(size_t)(row + r) * N + col] = val;
        } else {  // fused QKV routing (segment uniform across the 16-lane store group)
          if (col < 4096)      ((bf16*)Cp)[(size_t)(row + r) * 4096 + col] = __float2bfloat16(val * qmul);
          else if (col < 4608) ((bf16*)Cqp)[(size_t)(row + r) * 512 + (col - 4096)] = __float2bfloat16(val);
          else                 ((bf16*)Ctp)[(size_t)(col - 4608) * M + row + r] = __float2bfloat16(val);
        }
      }
    }
  }
}

// ---------------------------------------------------------------------------
// Fallback-path GEMM (fp32 inputs staged in-kernel). Unchanged, verified.
// ---------------------------------------------------------------------------
template <int A_BF, int B_BF, int OUT_MODE>
__global__ __launch_bounds__(256)
void gemm_bt_bias(const void* __restrict__ Ap, const void* __restrict__ Bp,
                  const float* __restrict__ bias, void* __restrict__ Cp,
                  void* __restrict__ Cqp, void* __restrict__ Ctp,
                  int M, int N, int K, float qmul) {
  __shared__ __align__(16) bf16 sA[128 * 32];
  __shared__ __align__(16) bf16 sB[128 * 32];
  const int tid  = threadIdx.x;
  const int wave = tid >> 6;
  const int lane = tid & 63;
  const int quad = lane >> 4;
  const int l15  = lane & 15;
  const int bm = blockIdx.y * 128;
  const int bn = blockIdx.x * 128;
  const int wm = (wave & 1) * 64;
  const int wn = (wave >> 1) * 64;

  floatx4 acc[4][4] = {};

  const int g0 = tid, g1 = tid + 256;
  const int arow0 = bm + (g0 >> 2), acol0 = (g0 & 3) * 8;
  const int arow1 = bm + (g1 >> 2), acol1 = (g1 & 3) * 8;
  int brow0 = bn + (g0 >> 2); if (brow0 >= N) brow0 = N - 1;
  int brow1 = bn + (g1 >> 2); if (brow1 >= N) brow1 = N - 1;

  for (int k0 = 0; k0 < K; k0 += 32) {
    __syncthreads();
    if (A_BF) {
      const bf16* A = (const bf16*)Ap;
      async_ld16(A + (size_t)arow0 * K + k0 + acol0, sA + wave * 512);
      async_ld16(A + (size_t)arow1 * K + k0 + acol1, sA + 2048 + wave * 512);
    } else {
      const float* A = (const float*)Ap;
      const float* p0 = A + (size_t)arow0 * K + k0 + acol0;
      const float* p1 = A + (size_t)arow1 * K + k0 + acol1;
      *(uint4*)(sA + tid * 8)        = pack8(*(const float4*)p0, *(const float4*)(p0 + 4));
      *(uint4*)(sA + 2048 + tid * 8) = pack8(*(const float4*)p1, *(const float4*)(p1 + 4));
    }
    if (B_BF) {
      const bf16* B = (const bf16*)Bp;
      async_ld16(B + (size_t)brow0 * K + k0 + acol0, sB + wave * 512);
      async_ld16(B + (size_t)brow1 * K + k0 + acol1, sB + 2048 + wave * 512);
    } else {
      const float* B = (const float*)Bp;
      const float* p0 = B + (size_t)brow0 * K + k0 + acol0;
      const float* p1 = B + (size_t)brow1 * K + k0 + acol1;
      *(uint4*)(sB + tid * 8)        = pack8(*(const float4*)p0, *(const float4*)(p0 + 4));
      *(uint4*)(sB + 2048 + tid * 8) = pack8(*(const float4*)p1, *(const float4*)(p1 + 4));
    }
    __syncthreads();

    bf16x8 aF[4], bF[4];
#pragma unroll
    for (int mi = 0; mi < 4; ++mi)
      aF[mi] = *(const bf16x8*)(sA + (wm + mi * 16 + l15) * 32 + quad * 8);
#pragma unroll
    for (int ni = 0; ni < 4; ++ni)
      bF[ni] = *(const bf16x8*)(sB + (wn + ni * 16 + l15) * 32 + quad * 8);
#pragma unroll
    for (int mi = 0; mi < 4; ++mi)
#pragma unroll
      for (int ni = 0; ni < 4; ++ni)
        acc[mi][ni] = mfma16(aF[mi], bF[ni], acc[mi][ni]);
  }

#pragma unroll
  for (int ni = 0; ni < 4; ++ni) {
    const int col = bn + wn + ni * 16 + l15;
    if (col >= N) continue;
    const float bv = bias[col];
#pragma unroll
    for (int mi = 0; mi < 4; ++mi) {
      const int row = bm + wm + mi * 16 + quad * 4;
#pragma unroll
      for (int r = 0; r < 4; ++r) {
        const float val = acc[mi][ni][r] + bv;
        if (OUT_MODE == 0) {
          ((bf16*)Cp)[(size_t)(row + r) * N + col] = __float2bfloat16(val * qmul);
        } else if (OUT_MODE == 1) {
          ((float*)Cp)[(size_t)(row + r) * N + col] = val;
        } else if (OUT_MODE == 2) {
          ((bf16*)Ctp)[(size_t)col * M + row + r] = __float2bfloat16(val);
        }
      }
    }
  }
}

// Fused causal GQA attention, flash-style online softmax (exp2 domain; Q pre-scaled).
// 4 waves; swapped MFMA operands: query is lane-local (see round-8 notes).
// XCD-aware block swizzle — XCD k owns heads 8k..8k+7 (one KV group, 512 KB,
// L2-resident per XCD; verified round-9: FETCH 22.9 -> 10.3 GB, 153 -> 108 us).
__global__ __launch_bounds__(256)
void attn_fused(const bf16* __restrict__ Q, const bf16* __restrict__ Kc,
                const bf16* __restrict__ Vt, bf16* __restrict__ AO) {
  constexpr int HD = 4096, KD = 512, SEQ = 2048;
  constexpr float NEG = -1e30f;
  __shared__ __align__(16) bf16 sP[64 * 64];       // [query][key], swizzled granules
  __shared__ __align__(16) bf16 sK[2][64 * 64];    // [t][d], swizzled granules
  __shared__ __align__(16) bf16 sV[2][64 * 64];    // [d][t], swizzled granules

  // grid (32, 64) -> 2048 blocks; XCD swizzle: L = (lin&7)*256 + lin>>3
  const int lin = blockIdx.y * 32 + blockIdx.x;
  const int L   = (lin & 7) * 256 + (lin >> 3);
  const int h   = L >> 5;                           // heads 8k..8k+7 on XCD k
  const int qb  = 31 - (L & 31);                    // heavy blocks first within head
  const int kvh = h >> 3;        // h // G, G=8
  const int tid = threadIdx.x, wave = tid >> 6, lane = tid & 63;
  const int quad = lane >> 4, l15 = lane & 15;
  const int sq0 = qb * 64;

  // DMA decomposition: chunk c = wave*2+i covers tile rows 8c..8c+7.
  const int lrow = lane >> 3;
  const int lgr  = (lane & 7) ^ lrow;

  // Q fragments straight to registers (lane l15 = query row wave*16+l15)
  bf16x8 qf[2];
#pragma unroll
  for (int ks = 0; ks < 2; ++ks)
    qf[ks] = *(const bf16x8*)(Q + (size_t)(sq0 + wave * 16 + l15) * HD + h * 64 + ks * 32 + quad * 8);

  // ones A-fragment for the key-sum MFMA (denominator)
  bf16x8 onesf;
#pragma unroll
  for (int i = 0; i < 8; ++i) onesf[i] = (__bf16)1.0f;

  // prologue: DMA tile 0 into buffer 0
#pragma unroll
  for (int i = 0; i < 2; ++i) {
    const int c = wave * 2 + i;
    async_ld16(Kc + (size_t)(c * 8 + lrow) * KD + kvh * 64 + lgr * 8, &sK[0][c * 512]);
    async_ld16(Vt + (size_t)(kvh * 64 + c * 8 + lrow) * SEQ + lgr * 8, &sV[0][c * 512]);
  }

  floatx4 o_acc[4] = {};   // O^T: lane = query, o_acc[di][r] = O[q][di*16+quad*4+r]
  floatx4 o_sum = {};      // denominator (all 4 regs equal), lane = query
  float m_run = NEG;       // per-lane scalar running max (lane's query)

  for (int kt = 0; kt <= qb; ++kt) {   // analytic causality: skip fully-masked key tiles
    const int st0 = kt * 64;
    __syncthreads();  // drains tile-kt DMA (vmcnt) for all waves; protects buffer reuse

    if (kt < qb) {    // issue tile kt+1 DMA; in flight through this compute phase
      const int st1 = st0 + 64;
      const int nb = (kt + 1) & 1;
#pragma unroll
      for (int i = 0; i < 2; ++i) {
        const int c = wave * 2 + i;
        async_ld16(Kc + (size_t)(st1 + c * 8 + lrow) * KD + kvh * 64 + lgr * 8, &sK[nb][c * 512]);
        async_ld16(Vt + (size_t)(kvh * 64 + c * 8 + lrow) * SEQ + st1 + lgr * 8, &sV[nb][c * 512]);
      }
    }
    const bf16* kb = sK[kt & 1];
    const bf16* vb = sV[kt & 1];

    // S^T = K Q^T : lane l15 = query, s_acc[ni][r] = key st0+ni*16+quad*4+r
    floatx4 s_acc[4] = {};
#pragma unroll
    for (int ks = 0; ks < 2; ++ks) {
#pragma unroll
      for (int ni = 0; ni < 4; ++ni) {
        const bf16x8 kF = *(const bf16x8*)(kb + (ni * 16 + l15) * 64 + (((ks * 4 + quad) ^ (l15 & 7)) * 8));
        s_acc[ni] = mfma16(kF, qf[ks], s_acc[ni]);
      }
    }

    if (kt == qb) {   // diagonal tile only: causal mask key > query (wave-uniform branch)
      const int qloc = wave * 16 + l15;
#pragma unroll
      for (int ni = 0; ni < 4; ++ni)
#pragma unroll
        for (int r = 0; r < 4; ++r)
          if (ni * 16 + quad * 4 + r > qloc) s_acc[ni][r] = NEG;
    }

    // row max: 15 lane-local fmax (tree) + 2 cross-quad shfl
    float t0 = fmaxf(fmaxf(s_acc[0][0], s_acc[0][1]), fmaxf(s_acc[0][2], s_acc[0][3]));
    float t1 = fmaxf(fmaxf(s_acc[1][0], s_acc[1][1]), fmaxf(s_acc[1][2], s_acc[1][3]));
    float t2 = fmaxf(fmaxf(s_acc[2][0], s_acc[2][1]), fmaxf(s_acc[2][2], s_acc[2][3]));
    float t3 = fmaxf(fmaxf(s_acc[3][0], s_acc[3][1]), fmaxf(s_acc[3][2], s_acc[3][3]));
    float tm = fmaxf(fmaxf(t0, t1), fmaxf(t2, t3));
    tm = fmaxf(tm, __shfl_xor(tm, 16));
    tm = fmaxf(tm, __shfl_xor(tm, 32));

    // defer-max: rescale only when some lane's max grew by > 8 (exp2 domain)
    if (!__all(tm - m_run <= 8.0f)) {
      const float mn = fmaxf(m_run, tm);
      const float alpha = exp2f(m_run - mn);
      m_run = mn;
#pragma unroll
      for (int r = 0; r < 4; ++r) o_sum[r] *= alpha;
#pragma unroll
      for (int di = 0; di < 4; ++di)
#pragma unroll
        for (int r = 0; r < 4; ++r) o_acc[di][r] *= alpha;
    }

    // P[query][key] -> swizzled sP; 4 consecutive keys pack into one b64 write
    const int prow = wave * 16 + l15;
#pragma unroll
    for (int ni = 0; ni < 4; ++ni) {
      union { uint2 u; bf16 hh[4]; } pk;
#pragma unroll
      for (int r = 0; r < 4; ++r)
        pk.hh[r] = __float2bfloat16(exp2f(s_acc[ni][r] - m_run));
      const int g = ni * 2 + (quad >> 1);
      *(uint2*)(sP + prow * 64 + ((g ^ (l15 & 7)) * 8) + (quad & 1) * 4) = pk.u;
    }

    // O^T += V^T P : lane = query; V reads identical pattern to QK^T's K reads
#pragma unroll
    for (int ks = 0; ks < 2; ++ks) {
      const bf16x8 pF = *(const bf16x8*)(sP + prow * 64 + (((ks * 4 + quad) ^ (l15 & 7)) * 8));
#pragma unroll
      for (int di = 0; di < 4; ++di) {
        const bf16x8 vF = *(const bf16x8*)(vb + (di * 16 + l15) * 64 + (((ks * 4 + quad) ^ (l15 & 7)) * 8));
        o_acc[di] = mfma16(vF, pF, o_acc[di]);
      }
      o_sum = mfma16(onesf, pF, o_sum);   // key-sum on the matrix pipe
    }
  }

  // normalize (1 rcp per lane) + packed 8B stores to AO[q][h*64+d]
  const float inv = 1.0f / o_sum[0];
  const int row = sq0 + wave * 16 + l15;
#pragma unroll
  for (int di = 0; di < 4; ++di) {
    union { uint2 u; bf16 hh[4]; } pk;
#pragma unroll
    for (int r = 0; r < 4; ++r)
      pk.hh[r] = __float2bfloat16(o_acc[di][r] * inv);
    *(uint2*)(AO + (size_t)row * HD + h * 64 + di * 16 + quad * 4) = pk.u;
  }
}

extern "C" void kernel_launch(void* const* d_in, const int* in_sizes, int n_in,
                              void* d_out, int out_size, void* d_ws, size_t ws_size,
                              hipStream_t stream) {
  const float* X  = (const float*)d_in[0];   // [2048, 2880]
  // d_in[1] = attention_mask: exactly causal -> handled analytically
  const float* Wq = (const float*)d_in[2];   // [4096, 2880]
  const float* bq = (const float*)d_in[3];
  const float* Wk = (const float*)d_in[4];   // [512, 2880]
  const float* bk = (const float*)d_in[5];
  const float* Wv = (const float*)d_in[6];
  const float* bv = (const float*)d_in[7];
  const float* Wo = (const float*)d_in[8];   // [2880, 4096]
  const float* bo = (const float*)d_in[9];
  float* out = (float*)d_out;                // [2048, 2880] fp32

  char* ws = (char*)d_ws;
  bf16* Qb = (bf16*)(ws);                          // 16 MiB
  bf16* Kb = (bf16*)(ws + 16777216);               // [2048][512]  2 MiB
  bf16* Vt = (bf16*)(ws + 18874368);               // [512][2048]  2 MiB (transposed)
  bf16* AO = (bf16*)(ws + 20971520);               // 16 MiB
  // fast-path extras
  bf16*  Xb   = (bf16*)(ws + 37748736);            // 11.25 MiB
  bf16*  Wall = (bf16*)(ws + 49545216);            // [5120][2880] 29.5 MB (Wq|Wk|Wv)
  bf16*  Wob  = (bf16*)(ws + 79036416);            // 22.5 MiB
  const size_t NEED = 102629376;

  dim3 blk(256);
  if (ws_size >= NEED) {
    // one merged fp32->bf16 conversion pass (X + Wq|Wk|Wv + Wo), then bf16 GEMMs
    cvt_all<<<dim3(15840), blk, 0, stream>>>(X, Wq, Wk, Wv, Wo, Xb, Wall, Wob);

    // fused QKV projection: N = 4096 + 512 + 512; Q segment pre-scaled
    gemm_bt_db<4><<<dim3(40, 16), blk, 0, stream>>>(Xb, Wall, bq, bk, bv, Qb, Kb, Vt, 2048, 5120, 2880, QSCALE);
    attn_fused<<<dim3(32, 64), blk, 0, stream>>>(Qb, Kb, Vt, AO);
    gemm_bt_db<1><<<dim3(23, 16), blk, 0, stream>>>(AO, Wob, bo, nullptr, nullptr, out, nullptr, nullptr, 2048, 2880, 4096, 1.f);
  } else {
    // fallback: fp32 staging in-GEMM (round-3 verified path), V written transposed
    gemm_bt_bias<0, 0, 0><<<dim3(32, 16), blk, 0, stream>>>(X, Wq, bq, Qb, nullptr, nullptr, 2048, 4096, 2880, QSCALE);
    gemm_bt_bias<0, 0, 0><<<dim3(4, 16),  blk, 0, stream>>>(X, Wk, bk, Kb, nullptr, nullptr, 2048, 512, 2880, 1.f);
    gemm_bt_bias<0, 0, 2><<<dim3(4, 16),  blk, 0, stream>>>(X, Wv, bv, nullptr, nullptr, Vt, 2048, 512, 2880, 1.f);
    attn_fused<<<dim3(32, 64), blk, 0, stream>>>(Qb, Kb, Vt, AO);
    gemm_bt_bias<1, 0, 1><<<dim3(23, 16), blk, 0, stream>>>(AO, Wo, bo, out, nullptr, nullptr, 2048, 2880, 4096, 1.f);
  }
}